// Round 10
// baseline (309.174 us; speedup 1.0000x reference)
//
#include <hip/hip_runtime.h>
#include <hip/hip_fp16.h>
#include <math.h>
#include <float.h>

// Problem constants (from reference)
#define NN 20000      // nodes
#define EE 640000     // edges
#define HH 2          // heads
#define DD 64         // dim
#define LL 4          // layers
#define HD 128        // H*D
#define CAP 80        // fixed per-node edge-slot capacity (Poisson(32): max deg ~57)
#define GR 32         // rows per gemm block
#define GEMM_BLOCKS (NN / GR)          // 625
#define SCAT_BLOCKS ((EE + 255) / 256) // 2500
#define WCVT_BLOCKS 24                 // 3 layers x 2048 half8-chunks / 256 thr
#define NPB 4         // nodes per fused_aggregate block (256 threads, 1 wave/node)
#define LOG2E 1.4426950408889634f

// NOTE: "half2" is taken by amd_hip_fp16.h (using half2 = __half2) -> use hh2.
typedef _Float16 hh2 __attribute__((ext_vector_type(2)));
typedef _Float16 half4 __attribute__((ext_vector_type(4)));
typedef _Float16 half8 __attribute__((ext_vector_type(8)));

#if __has_builtin(__builtin_amdgcn_fdot2)
#define FDOT2(a, b, c) __builtin_amdgcn_fdot2((a), (b), (c), false)
#else
#define FDOT2(a, b, c) fmaf((float)(a)[0], (float)(b)[0], \
                        fmaf((float)(a)[1], (float)(b)[1], (c)))
#endif

__device__ __forceinline__ half4 f2h(float a, float b, float c, float d) {
    half4 r;
    r.x = (_Float16)a; r.y = (_Float16)b; r.z = (_Float16)c; r.w = (_Float16)d;
    return r;
}

// ---------------- DPP helper: sum within each aligned 8-lane half-row ----------------
__device__ __forceinline__ float grp8_sum(float x) {
    int t;
    t = __builtin_amdgcn_update_dpp(0, __float_as_int(x), 0xB1, 0xF, 0xF, true);
    x += __int_as_float(t);
    t = __builtin_amdgcn_update_dpp(0, __float_as_int(x), 0x4E, 0xF, 0xF, true);
    x += __int_as_float(t);
    t = __builtin_amdgcn_update_dpp(0, __float_as_int(x), 0x141, 0xF, 0xF, true); // row_half_mirror
    x += __int_as_float(t);
    return x;
}

// ---------------- fused prep: layer-0 GEMM + slotted-CSR scatter + W fp16-transpose ----------------
// wt16 layout (per layer): half8 chunk index = kb*256 + col  (kb = k-block 0..7,
// col = output column 0..255). Lane l reading chunk kb*256+l gives consecutive
// lanes consecutive 16B -> perfectly coalesced L2 reads in the fused epilogue.
__global__ void __launch_bounds__(256) prep_kernel(
        const float* __restrict__ x,
        const float* __restrict__ Wl, const float* __restrict__ bl,
        const float* __restrict__ Wr, const float* __restrict__ br,
        _Float16* __restrict__ xl, _Float16* __restrict__ xr,
        const int* __restrict__ src, const int* __restrict__ dst,
        int* __restrict__ cnt, int* __restrict__ csr_src,
        _Float16* __restrict__ wt16) {
    int tid = threadIdx.x;
    if (blockIdx.x >= GEMM_BLOCKS + SCAT_BLOCKS) {
        // ---- W convert part: layers 1..3 -> fp16, [kb][col] chunk order ----
        int q = (blockIdx.x - GEMM_BLOCKS - SCAT_BLOCKS) * 256 + tid; // 0..6143
        int l = q >> 11;           // 0..2  (layer l+1)
        int r = q & 2047;
        int kb = r >> 8;           // 0..7
        int col = r & 255;         // 0..255
        const float* base = (col < HD)
            ? (Wl + (size_t)(l + 1) * DD * HD + col)
            : (Wr + (size_t)(l + 1) * DD * HD + (col - HD));
        base += (size_t)(kb * 8) * HD;
        half8 h;
        h[0] = (_Float16)base[0 * HD];
        h[1] = (_Float16)base[1 * HD];
        h[2] = (_Float16)base[2 * HD];
        h[3] = (_Float16)base[3 * HD];
        h[4] = (_Float16)base[4 * HD];
        h[5] = (_Float16)base[5 * HD];
        h[6] = (_Float16)base[6 * HD];
        h[7] = (_Float16)base[7 * HD];
        *(half8*)&wt16[(size_t)l * 16384 + (size_t)r * 8] = h;
        return;
    }
    if (blockIdx.x >= GEMM_BLOCKS) {
        // ---- scatter part ----
        int e = (blockIdx.x - GEMM_BLOCKS) * 256 + tid;
        if (e < EE) {
            int d = dst[e];
            int pos = atomicAdd(&cnt[d], 1);
            if (pos < CAP) csr_src[d * CAP + pos] = src[e];
        }
        return;
    }
    // ---- GEMM part (R10 structure) ----
    __shared__ float xs[16][GR];
    __shared__ float ws[16][2 * HD];
    int row0 = blockIdx.x * GR;
    int tc = tid & 63;
    int tr = tid >> 6;
    int c0 = tc * 4;

    float4 bv;
    {
        const float* bsrc = (c0 < HD) ? (bl + c0) : (br + (c0 - HD));
        bv = *(const float4*)bsrc;
    }
    float acc[8][4];
#pragma unroll
    for (int r = 0; r < 8; ++r) {
        acc[r][0] = bv.x; acc[r][1] = bv.y; acc[r][2] = bv.z; acc[r][3] = bv.w;
    }

    int sr = tid >> 3;
    int skk = (tid & 7) * 2;

    for (int kc = 0; kc < DD; kc += 16) {
        __syncthreads();
        {
            float2 v = *(const float2*)&x[(size_t)(row0 + sr) * DD + kc + skk];
            xs[skk][sr] = v.x;
            xs[skk + 1][sr] = v.y;
        }
#pragma unroll
        for (int q = 0; q < 4; ++q) {
            int idx = tid + 256 * q;
            int kk = idx >> 6;
            int cc = (idx & 63) * 4;
            const float* srcp = (cc < HD) ? (Wl + (size_t)(kc + kk) * HD + cc)
                                          : (Wr + (size_t)(kc + kk) * HD + (cc - HD));
            *(float4*)&ws[kk][cc] = *(const float4*)srcp;
        }
        __syncthreads();
#pragma unroll
        for (int kk = 0; kk < 16; ++kk) {
            float4 wv = *(const float4*)&ws[kk][c0];
            float xv[8];
            *(float4*)&xv[0] = *(const float4*)&xs[kk][tr * 8];
            *(float4*)&xv[4] = *(const float4*)&xs[kk][tr * 8 + 4];
#pragma unroll
            for (int r = 0; r < 8; ++r) {
                acc[r][0] = fmaf(xv[r], wv.x, acc[r][0]);
                acc[r][1] = fmaf(xv[r], wv.y, acc[r][1]);
                acc[r][2] = fmaf(xv[r], wv.z, acc[r][2]);
                acc[r][3] = fmaf(xv[r], wv.w, acc[r][3]);
            }
        }
    }

    _Float16* ybase = (c0 < HD) ? xl : xr;
    int cw = (c0 < HD) ? c0 : (c0 - HD);
#pragma unroll
    for (int r = 0; r < 8; ++r) {
        int row = row0 + tr * 8 + r;
        *(half4*)&ybase[(size_t)row * HD + cw] =
            f2h(acc[r][0], acc[r][1], acc[r][2], acc[r][3]);
    }
}

// Fused GATv2 edge phase, v10 = R9 + barrier-free NEXT epilogue:
//  - R9 evidence: one-barrier LDS epilogue converted (52->~41 us). Remaining
//    structure: 1 barrier + 36KB LDS W round-trip (8 writes + 32 reads per
//    thread) + LDS-halved occupancy. All removed here:
//  - W read DIRECTLY from L2 in [kb][col] chunk order -> 32 perfectly
//    coalesced 16B/lane loads, all issued up front (deep pipeline), pinned
//    by sched_barrier(0). Same FDOT2 summation order as R9 -> bit-identical.
//  - NEXT instantiation now has ZERO __syncthreads (sh_idx/sh_o16 are
//    wave-private); LDS 39->~3 KB.
//  - R5 fence retained: W loads must not hoist above the edge loop
//    (tripwire: WRITE_SIZE >> 10 MB, VGPR > 128).
template <bool FINAL>
__global__ void __launch_bounds__(256, 4) fused_aggregate(
        const _Float16* __restrict__ xl, const _Float16* __restrict__ xr,
        const float* __restrict__ att, const int* __restrict__ cnt,
        const int* __restrict__ csr_src, const float* __restrict__ bias,
        const _Float16* __restrict__ wtn, const float* __restrict__ bnl,
        const float* __restrict__ bnr,
        const float* __restrict__ Wo, const float* __restrict__ bo,
        _Float16* __restrict__ xlo, _Float16* __restrict__ xro,
        float* __restrict__ out) {
    int tid = threadIdx.x;
    int lane = tid & 63;
    int w = tid >> 6;                 // wave = node slot, 0..3
    int node = blockIdx.x * NPB + w;
    int g = lane >> 4;                // 4 groups of 16 lanes; group handles 2 edges/iter
    int hl = lane & 15;               // position in group: 0-7 head a, 8-15 head b
    int eo = hl * 8;                  // this lane's 8-elem slice of the 128-elem row

    __shared__ float    sh_o[NPB][DD];     // 1 KB (FINAL path)
    __shared__ _Float16 sh_o16[NPB][DD];   // 0.5 KB (NEXT path, wave-private)
    __shared__ int      sh_idx[NPB][CAP];  // 1.25 KB, per-node slot list (wave-private)

    int start = node * CAP;
    int deg = min(cnt[node], CAP);

    // stage this node's slot list (wave-private LDS region; no barrier needed)
    if (lane < CAP / 2) {
        *(int2*)&sh_idx[w][lane * 2] = *(const int2*)&csr_src[start + lane * 2];
    }
    // sentinel zero-fill of slots >= deg (covers [0,80) with lane and lane+64)
    if (lane >= deg) sh_idx[w][lane] = 0;
    {
        int t2 = lane + 64;
        if (t2 >= deg && t2 < CAP) sh_idx[w][t2] = 0;
    }

    unsigned nrow = (unsigned)node << 7;
    const _Float16* xl_eo = xl + eo;   // per-lane gather base, hoisted

    // per-lane xr slice (f32) and att slice (f32, log2e-folded) — named scalars
    float xr0, xr1, xr2, xr3, xr4, xr5, xr6, xr7;
    float at0, at1, at2, at3, at4, at5, at6, at7;
    {
        half8 xh = *(const half8*)&xr[nrow + eo];
        xr0 = (float)xh[0]; xr1 = (float)xh[1]; xr2 = (float)xh[2]; xr3 = (float)xh[3];
        xr4 = (float)xh[4]; xr5 = (float)xh[5]; xr6 = (float)xh[6]; xr7 = (float)xh[7];
        float4 a0 = *(const float4*)&att[eo];
        float4 a1 = *(const float4*)&att[eo + 4];
        at0 = a0.x * LOG2E; at1 = a0.y * LOG2E; at2 = a0.z * LOG2E; at3 = a0.w * LOG2E;
        at4 = a1.x * LOG2E; at5 = a1.y * LOG2E; at6 = a1.z * LOG2E; at7 = a1.w * LOG2E;
    }

    float s = 0.f;
    float ac0 = 0.f, ac1 = 0.f, ac2 = 0.f, ac3 = 0.f;
    float ac4 = 0.f, ac5 = 0.f, ac6 = 0.f, ac7 = 0.f;

    if (deg > 0) {
        int niter = (deg + 7) >> 3;

#define IDX2(k) (*(const int2*)&sh_idx[w][8 * min((k), CAP / 8 - 1) + 2 * g])

#define GATHER(H0, H1, k)                                                  \
        {                                                                  \
            int2 r_ = IDX2(k);                                             \
            H0 = *(const half8*)&xl_eo[(unsigned)r_.x << 7];               \
            H1 = *(const half8*)&xl_eo[(unsigned)r_.y << 7];               \
        }

        // fully hand-unrolled, literal indices only (scratch-proof);
        // leaky = fmaxf(v, 0.2f*v) (bit-identical 2-op form)
#define COMPUTE(H0, H1, k)                                                 \
        {                                                                  \
            float x00 = (float)H0[0], x01 = (float)H0[1];                  \
            float x02 = (float)H0[2], x03 = (float)H0[3];                  \
            float x04 = (float)H0[4], x05 = (float)H0[5];                  \
            float x06 = (float)H0[6], x07 = (float)H0[7];                  \
            float x10 = (float)H1[0], x11 = (float)H1[1];                  \
            float x12 = (float)H1[2], x13 = (float)H1[3];                  \
            float x14 = (float)H1[4], x15 = (float)H1[5];                  \
            float x16 = (float)H1[6], x17 = (float)H1[7];                  \
            float v, t0 = 0.f, t1 = 0.f;                                   \
            v = x00 + xr0; v = fmaxf(v, 0.2f * v); t0 = fmaf(v, at0, t0);  \
            v = x01 + xr1; v = fmaxf(v, 0.2f * v); t0 = fmaf(v, at1, t0);  \
            v = x02 + xr2; v = fmaxf(v, 0.2f * v); t0 = fmaf(v, at2, t0);  \
            v = x03 + xr3; v = fmaxf(v, 0.2f * v); t0 = fmaf(v, at3, t0);  \
            v = x04 + xr4; v = fmaxf(v, 0.2f * v); t0 = fmaf(v, at4, t0);  \
            v = x05 + xr5; v = fmaxf(v, 0.2f * v); t0 = fmaf(v, at5, t0);  \
            v = x06 + xr6; v = fmaxf(v, 0.2f * v); t0 = fmaf(v, at6, t0);  \
            v = x07 + xr7; v = fmaxf(v, 0.2f * v); t0 = fmaf(v, at7, t0);  \
            v = x10 + xr0; v = fmaxf(v, 0.2f * v); t1 = fmaf(v, at0, t1);  \
            v = x11 + xr1; v = fmaxf(v, 0.2f * v); t1 = fmaf(v, at1, t1);  \
            v = x12 + xr2; v = fmaxf(v, 0.2f * v); t1 = fmaf(v, at2, t1);  \
            v = x13 + xr3; v = fmaxf(v, 0.2f * v); t1 = fmaf(v, at3, t1);  \
            v = x14 + xr4; v = fmaxf(v, 0.2f * v); t1 = fmaf(v, at4, t1);  \
            v = x15 + xr5; v = fmaxf(v, 0.2f * v); t1 = fmaf(v, at5, t1);  \
            v = x16 + xr6; v = fmaxf(v, 0.2f * v); t1 = fmaf(v, at6, t1);  \
            v = x17 + xr7; v = fmaxf(v, 0.2f * v); t1 = fmaf(v, at7, t1);  \
            t0 = grp8_sum(t0);                                             \
            t1 = grp8_sum(t1);                                             \
            int sl_ = 8 * (k) + 2 * g;                                     \
            float w0 = (sl_ < deg) ? exp2f(t0) : 0.f;                      \
            float w1 = (sl_ + 1 < deg) ? exp2f(t1) : 0.f;                  \
            s += w0 + w1;                                                  \
            ac0 = fmaf(w0, x00, fmaf(w1, x10, ac0));                       \
            ac1 = fmaf(w0, x01, fmaf(w1, x11, ac1));                       \
            ac2 = fmaf(w0, x02, fmaf(w1, x12, ac2));                       \
            ac3 = fmaf(w0, x03, fmaf(w1, x13, ac3));                       \
            ac4 = fmaf(w0, x04, fmaf(w1, x14, ac4));                       \
            ac5 = fmaf(w0, x05, fmaf(w1, x15, ac5));                       \
            ac6 = fmaf(w0, x06, fmaf(w1, x16, ac6));                       \
            ac7 = fmaf(w0, x07, fmaf(w1, x17, ac7));                       \
        }

        half8 A0, A1, B0, B1, C0, C1, D0, D1;

        GATHER(A0, A1, 0);
        GATHER(B0, B1, 1);
        GATHER(C0, C1, 2);

        int it = 0;
        while (true) {
            {
                GATHER(D0, D1, it + 3);
                __builtin_amdgcn_sched_barrier(0);
                COMPUTE(A0, A1, it);
            }
            if (++it == niter) break;
            {
                GATHER(A0, A1, it + 3);
                __builtin_amdgcn_sched_barrier(0);
                COMPUTE(B0, B1, it);
            }
            if (++it == niter) break;
            {
                GATHER(B0, B1, it + 3);
                __builtin_amdgcn_sched_barrier(0);
                COMPUTE(C0, C1, it);
            }
            if (++it == niter) break;
            {
                GATHER(C0, C1, it + 3);
                __builtin_amdgcn_sched_barrier(0);
                COMPUTE(D0, D1, it);
            }
            if (++it == niter) break;
        }
#undef IDX2
#undef GATHER
#undef COMPUTE
    }

    // fence: nothing below (esp. epilogue W loads) may move above the edge
    // loop (R5 hoist -> per-iteration spill lesson)
    asm volatile("" ::: "memory");
    __builtin_amdgcn_sched_barrier(0);

    // merge the 4 group partials: plain sums (no max tracking needed)
#pragma unroll
    for (int off = 16; off <= 32; off <<= 1) {
        s   += __shfl_xor(s, off);
        ac0 += __shfl_xor(ac0, off);
        ac1 += __shfl_xor(ac1, off);
        ac2 += __shfl_xor(ac2, off);
        ac3 += __shfl_xor(ac3, off);
        ac4 += __shfl_xor(ac4, off);
        ac5 += __shfl_xor(ac5, off);
        ac6 += __shfl_xor(ac6, off);
        ac7 += __shfl_xor(ac7, off);
    }

    // head mean: lane hl pairs with hl^8 (same elem slot, other head)
    float so  = __shfl_xor(s, 8);
    float ot0 = __shfl_xor(ac0, 8);
    float ot1 = __shfl_xor(ac1, 8);
    float ot2 = __shfl_xor(ac2, 8);
    float ot3 = __shfl_xor(ac3, 8);
    float ot4 = __shfl_xor(ac4, 8);
    float ot5 = __shfl_xor(ac5, 8);
    float ot6 = __shfl_xor(ac6, 8);
    float ot7 = __shfl_xor(ac7, 8);

    // node output o = leaky(0.5*(h0+h1) + bias, 0.01) -> LDS (lanes 0-7 of wave)
    if (lane < 8) {
        float inv0 = 1.0f / (s + 1e-16f);    // own = head a
        float inv1 = 1.0f / (so + 1e-16f);   // other = head b
        float4 bv0 = *(const float4*)&bias[lane * 8];
        float4 bv1 = *(const float4*)&bias[lane * 8 + 4];
        float o0 = fmaf(0.5f, fmaf(ac0, inv0, ot0 * inv1), bv0.x);
        float o1 = fmaf(0.5f, fmaf(ac1, inv0, ot1 * inv1), bv0.y);
        float o2 = fmaf(0.5f, fmaf(ac2, inv0, ot2 * inv1), bv0.z);
        float o3 = fmaf(0.5f, fmaf(ac3, inv0, ot3 * inv1), bv0.w);
        float o4 = fmaf(0.5f, fmaf(ac4, inv0, ot4 * inv1), bv1.x);
        float o5 = fmaf(0.5f, fmaf(ac5, inv0, ot5 * inv1), bv1.y);
        float o6 = fmaf(0.5f, fmaf(ac6, inv0, ot6 * inv1), bv1.z);
        float o7 = fmaf(0.5f, fmaf(ac7, inv0, ot7 * inv1), bv1.w);
        o0 = o0 > 0.f ? o0 : 0.01f * o0;
        o1 = o1 > 0.f ? o1 : 0.01f * o1;
        o2 = o2 > 0.f ? o2 : 0.01f * o2;
        o3 = o3 > 0.f ? o3 : 0.01f * o3;
        o4 = o4 > 0.f ? o4 : 0.01f * o4;
        o5 = o5 > 0.f ? o5 : 0.01f * o5;
        o6 = o6 > 0.f ? o6 : 0.01f * o6;
        o7 = o7 > 0.f ? o7 : 0.01f * o7;
        if (FINAL) {
            *(float4*)&sh_o[w][lane * 8]     = make_float4(o0, o1, o2, o3);
            *(float4*)&sh_o[w][lane * 8 + 4] = make_float4(o4, o5, o6, o7);
        } else {
            half8 h;
            h[0] = (_Float16)o0; h[1] = (_Float16)o1;
            h[2] = (_Float16)o2; h[3] = (_Float16)o3;
            h[4] = (_Float16)o4; h[5] = (_Float16)o5;
            h[6] = (_Float16)o6; h[7] = (_Float16)o7;
            *(half8*)&sh_o16[w][lane * 8] = h;
        }
    }

    if (FINAL) {
        // stage Wo (64x64 = 16 KB) into LDS, then per-wave GEMV (verbatim R4)
        __shared__ float wlin[DD * DD];
        {
            int idx = tid * 16;  // 256 threads x 16 floats = 4096
            *(float4*)&wlin[idx]      = *(const float4*)&Wo[idx];
            *(float4*)&wlin[idx + 4]  = *(const float4*)&Wo[idx + 4];
            *(float4*)&wlin[idx + 8]  = *(const float4*)&Wo[idx + 8];
            *(float4*)&wlin[idx + 12] = *(const float4*)&Wo[idx + 12];
        }
        __syncthreads();
        int j = lane;
        float og = bo[j];
#pragma unroll 8
        for (int k = 0; k < DD; ++k) {
            og = fmaf(sh_o[w][k], wlin[k * DD + j], og);
        }
        og = og > 0.f ? og : 0.01f * og;
        out[(size_t)node * DD + j] = og;
    } else {
        // barrier-free fp16-dot2 epilogue: W read directly from L2 in
        // [kb][col] chunk order — 32 coalesced 16B/lane loads, issued up
        // front, pinned below the fence; then 8x16 FDOT2 (same summation
        // order as R9 -> bit-identical).
        const half8* wp = (const half8*)wtn;
        float a0 = bnl[lane];
        float a1 = bnl[lane + 64];
        float a2 = bnr[lane];
        float a3 = bnr[lane + 64];

        half8 w00 = wp[0 * 256 + lane], w01 = wp[0 * 256 + lane + 64],
              w02 = wp[0 * 256 + lane + 128], w03 = wp[0 * 256 + lane + 192];
        half8 w10 = wp[1 * 256 + lane], w11 = wp[1 * 256 + lane + 64],
              w12 = wp[1 * 256 + lane + 128], w13 = wp[1 * 256 + lane + 192];
        half8 w20 = wp[2 * 256 + lane], w21 = wp[2 * 256 + lane + 64],
              w22 = wp[2 * 256 + lane + 128], w23 = wp[2 * 256 + lane + 192];
        half8 w30 = wp[3 * 256 + lane], w31 = wp[3 * 256 + lane + 64],
              w32 = wp[3 * 256 + lane + 128], w33 = wp[3 * 256 + lane + 192];
        half8 w40 = wp[4 * 256 + lane], w41 = wp[4 * 256 + lane + 64],
              w42 = wp[4 * 256 + lane + 128], w43 = wp[4 * 256 + lane + 192];
        half8 w50 = wp[5 * 256 + lane], w51 = wp[5 * 256 + lane + 64],
              w52 = wp[5 * 256 + lane + 128], w53 = wp[5 * 256 + lane + 192];
        half8 w60 = wp[6 * 256 + lane], w61 = wp[6 * 256 + lane + 64],
              w62 = wp[6 * 256 + lane + 128], w63 = wp[6 * 256 + lane + 192];
        half8 w70 = wp[7 * 256 + lane], w71 = wp[7 * 256 + lane + 64],
              w72 = wp[7 * 256 + lane + 128], w73 = wp[7 * 256 + lane + 192];
        __builtin_amdgcn_sched_barrier(0);  // keep all loads above the dots

#define KB(kb, wa, wb, wc, wd)                                             \
        {                                                                  \
            half8 o8 = *(const half8*)&sh_o16[w][(kb) * 8];                \
            hh2 oA = __builtin_shufflevector(o8, o8, 0, 1);                \
            hh2 oB = __builtin_shufflevector(o8, o8, 2, 3);                \
            hh2 oC = __builtin_shufflevector(o8, o8, 4, 5);                \
            hh2 oD = __builtin_shufflevector(o8, o8, 6, 7);                \
            a0 = FDOT2(__builtin_shufflevector(wa, wa, 0, 1), oA, a0);     \
            a0 = FDOT2(__builtin_shufflevector(wa, wa, 2, 3), oB, a0);     \
            a0 = FDOT2(__builtin_shufflevector(wa, wa, 4, 5), oC, a0);     \
            a0 = FDOT2(__builtin_shufflevector(wa, wa, 6, 7), oD, a0);     \
            a1 = FDOT2(__builtin_shufflevector(wb, wb, 0, 1), oA, a1);     \
            a1 = FDOT2(__builtin_shufflevector(wb, wb, 2, 3), oB, a1);     \
            a1 = FDOT2(__builtin_shufflevector(wb, wb, 4, 5), oC, a1);     \
            a1 = FDOT2(__builtin_shufflevector(wb, wb, 6, 7), oD, a1);     \
            a2 = FDOT2(__builtin_shufflevector(wc, wc, 0, 1), oA, a2);     \
            a2 = FDOT2(__builtin_shufflevector(wc, wc, 2, 3), oB, a2);     \
            a2 = FDOT2(__builtin_shufflevector(wc, wc, 4, 5), oC, a2);     \
            a2 = FDOT2(__builtin_shufflevector(wc, wc, 6, 7), oD, a2);     \
            a3 = FDOT2(__builtin_shufflevector(wd, wd, 0, 1), oA, a3);     \
            a3 = FDOT2(__builtin_shufflevector(wd, wd, 2, 3), oB, a3);     \
            a3 = FDOT2(__builtin_shufflevector(wd, wd, 4, 5), oC, a3);     \
            a3 = FDOT2(__builtin_shufflevector(wd, wd, 6, 7), oD, a3);     \
        }
        KB(0, w00, w01, w02, w03)
        KB(1, w10, w11, w12, w13)
        KB(2, w20, w21, w22, w23)
        KB(3, w30, w31, w32, w33)
        KB(4, w40, w41, w42, w43)
        KB(5, w50, w51, w52, w53)
        KB(6, w60, w61, w62, w63)
        KB(7, w70, w71, w72, w73)
#undef KB

        size_t nb = (size_t)node * HD;
        xlo[nb + lane]      = (_Float16)a0;
        xlo[nb + lane + 64] = (_Float16)a1;
        xro[nb + lane]      = (_Float16)a2;
        xro[nb + lane + 64] = (_Float16)a3;
    }
}

extern "C" void kernel_launch(void* const* d_in, const int* in_sizes, int n_in,
                              void* d_out, int out_size, void* d_ws, size_t ws_size,
                              hipStream_t stream) {
    const int* edge_index = (const int*)d_in[0];
    const int* src = edge_index;
    const int* dst = edge_index + EE;
    // d_in[1] = edge_weight, unused
    const float* pert = (const float*)d_in[2];
    const float* Wl = (const float*)d_in[3];
    const float* bl = (const float*)d_in[4];
    const float* Wr = (const float*)d_in[5];
    const float* br = (const float*)d_in[6];
    const float* att = (const float*)d_in[7];
    const float* bias = (const float*)d_in[8];
    const float* Wo = (const float*)d_in[9];
    const float* bo = (const float*)d_in[10];
    float* out = (float*)d_out;

    // workspace carve-up (A/B double-buffered fp16 transform tables)
    char* w = (char*)d_ws;
    _Float16* xlA = (_Float16*)w;     w += (size_t)NN * HD * 2;
    _Float16* xrA = (_Float16*)w;     w += (size_t)NN * HD * 2;
    _Float16* xlB = (_Float16*)w;     w += (size_t)NN * HD * 2;
    _Float16* xrB = (_Float16*)w;     w += (size_t)NN * HD * 2;
    int* cnt = (int*)w;               w += (size_t)NN * 4;
    int* csr_src = (int*)w;           w += (size_t)NN * CAP * 4;
    _Float16* wt16 = (_Float16*)w;    w += (size_t)3 * 256 * DD * 2;  // 96 KB

    // memset cnt, then one combined launch: GEMM + scatter + W convert
    hipMemsetAsync(cnt, 0, (size_t)NN * 4, stream);
    prep_kernel<<<GEMM_BLOCKS + SCAT_BLOCKS + WCVT_BLOCKS, 256, 0, stream>>>(
        pert, Wl, bl, Wr, br, xlA, xrA, src, dst, cnt, csr_src, wt16);

    _Float16* xls[2] = {xlA, xlB};
    _Float16* xrs[2] = {xrA, xrB};
    for (int l = 0; l < LL - 1; ++l) {
        fused_aggregate<false><<<NN / NPB, 256, 0, stream>>>(
            xls[l & 1], xrs[l & 1], att + (size_t)l * HD, cnt, csr_src,
            bias + (size_t)l * DD,
            wt16 + (size_t)l * 16384,
            bl + (size_t)(l + 1) * HD, br + (size_t)(l + 1) * HD,
            nullptr, nullptr,
            xls[(l + 1) & 1], xrs[(l + 1) & 1], nullptr);
    }
    fused_aggregate<true><<<NN / NPB, 256, 0, stream>>>(
        xls[(LL - 1) & 1], xrs[(LL - 1) & 1], att + (size_t)(LL - 1) * HD, cnt, csr_src,
        bias + (size_t)(LL - 1) * DD,
        nullptr, nullptr, nullptr,
        Wo, bo, nullptr, nullptr, out);
}

// Round 11
// 258.199 us; speedup vs baseline: 1.1974x; 1.1974x over previous
//
#include <hip/hip_runtime.h>
#include <hip/hip_fp16.h>
#include <math.h>
#include <float.h>

// Problem constants (from reference)
#define NN 20000      // nodes
#define EE 640000     // edges
#define HH 2          // heads
#define DD 64         // dim
#define LL 4          // layers
#define HD 128        // H*D
#define CAP 80        // fixed per-node edge-slot capacity (Poisson(32): max deg ~57)
#define GR 32         // rows per gemm block
#define GEMM_BLOCKS (NN / GR)          // 625
#define SCAT_BLOCKS (EE / 1024)        // 625 (4 edges/thread x 256 threads)
#define WCVT_BLOCKS 24                 // 3 layers x 2048 half8-chunks / 256 thr
#define NPB 4         // nodes per fused_aggregate block (256 threads, 1 wave/node)
#define LOG2E 1.4426950408889634f
#define PADK 72       // LDS stride (fp16 elems) per W column: 144B = 16B*9, conflict-free b128

// NOTE: "half2" is taken by amd_hip_fp16.h (using half2 = __half2) -> use hh2.
typedef _Float16 hh2 __attribute__((ext_vector_type(2)));
typedef _Float16 half4 __attribute__((ext_vector_type(4)));
typedef _Float16 half8 __attribute__((ext_vector_type(8)));

#if __has_builtin(__builtin_amdgcn_fdot2)
#define FDOT2(a, b, c) __builtin_amdgcn_fdot2((a), (b), (c), false)
#else
#define FDOT2(a, b, c) fmaf((float)(a)[0], (float)(b)[0], \
                        fmaf((float)(a)[1], (float)(b)[1], (c)))
#endif

__device__ __forceinline__ half4 f2h(float a, float b, float c, float d) {
    half4 r;
    r.x = (_Float16)a; r.y = (_Float16)b; r.z = (_Float16)c; r.w = (_Float16)d;
    return r;
}

// ---------------- DPP helper: sum within each aligned 8-lane half-row ----------------
__device__ __forceinline__ float grp8_sum(float x) {
    int t;
    t = __builtin_amdgcn_update_dpp(0, __float_as_int(x), 0xB1, 0xF, 0xF, true);
    x += __int_as_float(t);
    t = __builtin_amdgcn_update_dpp(0, __float_as_int(x), 0x4E, 0xF, 0xF, true);
    x += __int_as_float(t);
    t = __builtin_amdgcn_update_dpp(0, __float_as_int(x), 0x141, 0xF, 0xF, true); // row_half_mirror
    x += __int_as_float(t);
    return x;
}

// ---------------- fused prep: layer-0 GEMM + slotted-CSR scatter + W fp16-transpose ----------------
// R10 lesson: NEXT epilogue must stay LDS-staged (R9 form) — direct-L2 W reads
// need 128 VGPR live and spill (WRITE_SIZE 10->70 MB). This file = R9 verbatim
// except the scatter branch: 4 edges/thread with int4 index loads (fewer waves,
// 4 independent atomic->store chains per thread for MLP).
__global__ void __launch_bounds__(256) prep_kernel(
        const float* __restrict__ x,
        const float* __restrict__ Wl, const float* __restrict__ bl,
        const float* __restrict__ Wr, const float* __restrict__ br,
        _Float16* __restrict__ xl, _Float16* __restrict__ xr,
        const int* __restrict__ src, const int* __restrict__ dst,
        int* __restrict__ cnt, int* __restrict__ csr_src,
        _Float16* __restrict__ wt16) {
    int tid = threadIdx.x;
    if (blockIdx.x >= GEMM_BLOCKS + SCAT_BLOCKS) {
        // ---- W convert part: layers 1..3 -> fp16 transposed [col][kb] ----
        int q = (blockIdx.x - GEMM_BLOCKS - SCAT_BLOCKS) * 256 + tid; // 0..6143
        int l = q >> 11;           // 0..2  (layer l+1)
        int r = q & 2047;
        int col = r >> 3;          // 0..255
        int kb = r & 7;            // 0..7
        const float* base = (col < HD)
            ? (Wl + (size_t)(l + 1) * DD * HD + col)
            : (Wr + (size_t)(l + 1) * DD * HD + (col - HD));
        base += (size_t)(kb * 8) * HD;
        half8 h;
        h[0] = (_Float16)base[0 * HD];
        h[1] = (_Float16)base[1 * HD];
        h[2] = (_Float16)base[2 * HD];
        h[3] = (_Float16)base[3 * HD];
        h[4] = (_Float16)base[4 * HD];
        h[5] = (_Float16)base[5 * HD];
        h[6] = (_Float16)base[6 * HD];
        h[7] = (_Float16)base[7 * HD];
        *(half8*)&wt16[(size_t)l * 16384 + (size_t)r * 8] = h;
        return;
    }
    if (blockIdx.x >= GEMM_BLOCKS) {
        // ---- scatter part: 4 edges per thread ----
        int e0 = (blockIdx.x - GEMM_BLOCKS) * 1024 + tid * 4;
        if (e0 + 3 < EE) {
            int4 s4 = *(const int4*)&src[e0];
            int4 d4 = *(const int4*)&dst[e0];
            int p0 = atomicAdd(&cnt[d4.x], 1);
            int p1 = atomicAdd(&cnt[d4.y], 1);
            int p2 = atomicAdd(&cnt[d4.z], 1);
            int p3 = atomicAdd(&cnt[d4.w], 1);
            if (p0 < CAP) csr_src[d4.x * CAP + p0] = s4.x;
            if (p1 < CAP) csr_src[d4.y * CAP + p1] = s4.y;
            if (p2 < CAP) csr_src[d4.z * CAP + p2] = s4.z;
            if (p3 < CAP) csr_src[d4.w * CAP + p3] = s4.w;
        }
        return;
    }
    // ---- GEMM part (R10 structure) ----
    __shared__ float xs[16][GR];
    __shared__ float ws[16][2 * HD];
    int row0 = blockIdx.x * GR;
    int tc = tid & 63;
    int tr = tid >> 6;
    int c0 = tc * 4;

    float4 bv;
    {
        const float* bsrc = (c0 < HD) ? (bl + c0) : (br + (c0 - HD));
        bv = *(const float4*)bsrc;
    }
    float acc[8][4];
#pragma unroll
    for (int r = 0; r < 8; ++r) {
        acc[r][0] = bv.x; acc[r][1] = bv.y; acc[r][2] = bv.z; acc[r][3] = bv.w;
    }

    int sr = tid >> 3;
    int skk = (tid & 7) * 2;

    for (int kc = 0; kc < DD; kc += 16) {
        __syncthreads();
        {
            float2 v = *(const float2*)&x[(size_t)(row0 + sr) * DD + kc + skk];
            xs[skk][sr] = v.x;
            xs[skk + 1][sr] = v.y;
        }
#pragma unroll
        for (int q = 0; q < 4; ++q) {
            int idx = tid + 256 * q;
            int kk = idx >> 6;
            int cc = (idx & 63) * 4;
            const float* srcp = (cc < HD) ? (Wl + (size_t)(kc + kk) * HD + cc)
                                          : (Wr + (size_t)(kc + kk) * HD + (cc - HD));
            *(float4*)&ws[kk][cc] = *(const float4*)srcp;
        }
        __syncthreads();
#pragma unroll
        for (int kk = 0; kk < 16; ++kk) {
            float4 wv = *(const float4*)&ws[kk][c0];
            float xv[8];
            *(float4*)&xv[0] = *(const float4*)&xs[kk][tr * 8];
            *(float4*)&xv[4] = *(const float4*)&xs[kk][tr * 8 + 4];
#pragma unroll
            for (int r = 0; r < 8; ++r) {
                acc[r][0] = fmaf(xv[r], wv.x, acc[r][0]);
                acc[r][1] = fmaf(xv[r], wv.y, acc[r][1]);
                acc[r][2] = fmaf(xv[r], wv.z, acc[r][2]);
                acc[r][3] = fmaf(xv[r], wv.w, acc[r][3]);
            }
        }
    }

    _Float16* ybase = (c0 < HD) ? xl : xr;
    int cw = (c0 < HD) ? c0 : (c0 - HD);
#pragma unroll
    for (int r = 0; r < 8; ++r) {
        int row = row0 + tr * 8 + r;
        *(half4*)&ybase[(size_t)row * HD + cw] =
            f2h(acc[r][0], acc[r][1], acc[r][2], acc[r][3]);
    }
}

// Fused GATv2 edge phase — R9 verbatim (measured 258 us total):
//  - 8-lane-per-edge half8 gathers, 3-step DPP reduce, no-max exp2 softmax
//  - depth-3 gather pipeline with sched_barrier(0) pins
//  - one-barrier fp16-dot2 NEXT epilogue, W LDS-staged (R10 lesson: direct-L2
//    W reads spill; LDS round-trip + 1 barrier is cheaper than the VGPRs)
template <bool FINAL>
__global__ void __launch_bounds__(256, 4) fused_aggregate(
        const _Float16* __restrict__ xl, const _Float16* __restrict__ xr,
        const float* __restrict__ att, const int* __restrict__ cnt,
        const int* __restrict__ csr_src, const float* __restrict__ bias,
        const _Float16* __restrict__ wtn, const float* __restrict__ bnl,
        const float* __restrict__ bnr,
        const float* __restrict__ Wo, const float* __restrict__ bo,
        _Float16* __restrict__ xlo, _Float16* __restrict__ xro,
        float* __restrict__ out) {
    int tid = threadIdx.x;
    int lane = tid & 63;
    int w = tid >> 6;                 // wave = node slot, 0..3
    int node = blockIdx.x * NPB + w;
    int g = lane >> 4;                // 4 groups of 16 lanes; group handles 2 edges/iter
    int hl = lane & 15;               // position in group: 0-7 head a, 8-15 head b
    int eo = hl * 8;                  // this lane's 8-elem slice of the 128-elem row

    __shared__ float    sh_o[NPB][DD];     // 1 KB (FINAL path)
    __shared__ _Float16 sh_o16[NPB][DD];   // 0.5 KB (NEXT path)
    __shared__ int      sh_idx[NPB][CAP];  // 1.25 KB, per-node slot list

    int start = node * CAP;
    int deg = min(cnt[node], CAP);

    // stage this node's slot list (wave-private LDS region; no barrier needed)
    if (lane < CAP / 2) {
        *(int2*)&sh_idx[w][lane * 2] = *(const int2*)&csr_src[start + lane * 2];
    }
    // sentinel zero-fill of slots >= deg (covers [0,80) with lane and lane+64)
    if (lane >= deg) sh_idx[w][lane] = 0;
    {
        int t2 = lane + 64;
        if (t2 >= deg && t2 < CAP) sh_idx[w][t2] = 0;
    }

    unsigned nrow = (unsigned)node << 7;
    const _Float16* xl_eo = xl + eo;   // per-lane gather base, hoisted

    // per-lane xr slice (f32) and att slice (f32, log2e-folded) — named scalars
    float xr0, xr1, xr2, xr3, xr4, xr5, xr6, xr7;
    float at0, at1, at2, at3, at4, at5, at6, at7;
    {
        half8 xh = *(const half8*)&xr[nrow + eo];
        xr0 = (float)xh[0]; xr1 = (float)xh[1]; xr2 = (float)xh[2]; xr3 = (float)xh[3];
        xr4 = (float)xh[4]; xr5 = (float)xh[5]; xr6 = (float)xh[6]; xr7 = (float)xh[7];
        float4 a0 = *(const float4*)&att[eo];
        float4 a1 = *(const float4*)&att[eo + 4];
        at0 = a0.x * LOG2E; at1 = a0.y * LOG2E; at2 = a0.z * LOG2E; at3 = a0.w * LOG2E;
        at4 = a1.x * LOG2E; at5 = a1.y * LOG2E; at6 = a1.z * LOG2E; at7 = a1.w * LOG2E;
    }

    float s = 0.f;
    float ac0 = 0.f, ac1 = 0.f, ac2 = 0.f, ac3 = 0.f;
    float ac4 = 0.f, ac5 = 0.f, ac6 = 0.f, ac7 = 0.f;

    if (deg > 0) {
        int niter = (deg + 7) >> 3;

#define IDX2(k) (*(const int2*)&sh_idx[w][8 * min((k), CAP / 8 - 1) + 2 * g])

#define GATHER(H0, H1, k)                                                  \
        {                                                                  \
            int2 r_ = IDX2(k);                                             \
            H0 = *(const half8*)&xl_eo[(unsigned)r_.x << 7];               \
            H1 = *(const half8*)&xl_eo[(unsigned)r_.y << 7];               \
        }

        // fully hand-unrolled, literal indices only (scratch-proof);
        // leaky = fmaxf(v, 0.2f*v) (bit-identical 2-op form)
#define COMPUTE(H0, H1, k)                                                 \
        {                                                                  \
            float x00 = (float)H0[0], x01 = (float)H0[1];                  \
            float x02 = (float)H0[2], x03 = (float)H0[3];                  \
            float x04 = (float)H0[4], x05 = (float)H0[5];                  \
            float x06 = (float)H0[6], x07 = (float)H0[7];                  \
            float x10 = (float)H1[0], x11 = (float)H1[1];                  \
            float x12 = (float)H1[2], x13 = (float)H1[3];                  \
            float x14 = (float)H1[4], x15 = (float)H1[5];                  \
            float x16 = (float)H1[6], x17 = (float)H1[7];                  \
            float v, t0 = 0.f, t1 = 0.f;                                   \
            v = x00 + xr0; v = fmaxf(v, 0.2f * v); t0 = fmaf(v, at0, t0);  \
            v = x01 + xr1; v = fmaxf(v, 0.2f * v); t0 = fmaf(v, at1, t0);  \
            v = x02 + xr2; v = fmaxf(v, 0.2f * v); t0 = fmaf(v, at2, t0);  \
            v = x03 + xr3; v = fmaxf(v, 0.2f * v); t0 = fmaf(v, at3, t0);  \
            v = x04 + xr4; v = fmaxf(v, 0.2f * v); t0 = fmaf(v, at4, t0);  \
            v = x05 + xr5; v = fmaxf(v, 0.2f * v); t0 = fmaf(v, at5, t0);  \
            v = x06 + xr6; v = fmaxf(v, 0.2f * v); t0 = fmaf(v, at6, t0);  \
            v = x07 + xr7; v = fmaxf(v, 0.2f * v); t0 = fmaf(v, at7, t0);  \
            v = x10 + xr0; v = fmaxf(v, 0.2f * v); t1 = fmaf(v, at0, t1);  \
            v = x11 + xr1; v = fmaxf(v, 0.2f * v); t1 = fmaf(v, at1, t1);  \
            v = x12 + xr2; v = fmaxf(v, 0.2f * v); t1 = fmaf(v, at2, t1);  \
            v = x13 + xr3; v = fmaxf(v, 0.2f * v); t1 = fmaf(v, at3, t1);  \
            v = x14 + xr4; v = fmaxf(v, 0.2f * v); t1 = fmaf(v, at4, t1);  \
            v = x15 + xr5; v = fmaxf(v, 0.2f * v); t1 = fmaf(v, at5, t1);  \
            v = x16 + xr6; v = fmaxf(v, 0.2f * v); t1 = fmaf(v, at6, t1);  \
            v = x17 + xr7; v = fmaxf(v, 0.2f * v); t1 = fmaf(v, at7, t1);  \
            t0 = grp8_sum(t0);                                             \
            t1 = grp8_sum(t1);                                             \
            int sl_ = 8 * (k) + 2 * g;                                     \
            float w0 = (sl_ < deg) ? exp2f(t0) : 0.f;                      \
            float w1 = (sl_ + 1 < deg) ? exp2f(t1) : 0.f;                  \
            s += w0 + w1;                                                  \
            ac0 = fmaf(w0, x00, fmaf(w1, x10, ac0));                       \
            ac1 = fmaf(w0, x01, fmaf(w1, x11, ac1));                       \
            ac2 = fmaf(w0, x02, fmaf(w1, x12, ac2));                       \
            ac3 = fmaf(w0, x03, fmaf(w1, x13, ac3));                       \
            ac4 = fmaf(w0, x04, fmaf(w1, x14, ac4));                       \
            ac5 = fmaf(w0, x05, fmaf(w1, x15, ac5));                       \
            ac6 = fmaf(w0, x06, fmaf(w1, x16, ac6));                       \
            ac7 = fmaf(w0, x07, fmaf(w1, x17, ac7));                       \
        }

        half8 A0, A1, B0, B1, C0, C1, D0, D1;

        GATHER(A0, A1, 0);
        GATHER(B0, B1, 1);
        GATHER(C0, C1, 2);

        int it = 0;
        while (true) {
            {
                GATHER(D0, D1, it + 3);
                __builtin_amdgcn_sched_barrier(0);
                COMPUTE(A0, A1, it);
            }
            if (++it == niter) break;
            {
                GATHER(A0, A1, it + 3);
                __builtin_amdgcn_sched_barrier(0);
                COMPUTE(B0, B1, it);
            }
            if (++it == niter) break;
            {
                GATHER(B0, B1, it + 3);
                __builtin_amdgcn_sched_barrier(0);
                COMPUTE(C0, C1, it);
            }
            if (++it == niter) break;
            {
                GATHER(C0, C1, it + 3);
                __builtin_amdgcn_sched_barrier(0);
                COMPUTE(D0, D1, it);
            }
            if (++it == niter) break;
        }
#undef IDX2
#undef GATHER
#undef COMPUTE
    }

    // fence: nothing below (esp. epilogue W staging loads) may move above
    // the edge loop (R5 hoist -> per-iteration spill lesson)
    asm volatile("" ::: "memory");
    __builtin_amdgcn_sched_barrier(0);

    // merge the 4 group partials: plain sums (no max tracking needed)
#pragma unroll
    for (int off = 16; off <= 32; off <<= 1) {
        s   += __shfl_xor(s, off);
        ac0 += __shfl_xor(ac0, off);
        ac1 += __shfl_xor(ac1, off);
        ac2 += __shfl_xor(ac2, off);
        ac3 += __shfl_xor(ac3, off);
        ac4 += __shfl_xor(ac4, off);
        ac5 += __shfl_xor(ac5, off);
        ac6 += __shfl_xor(ac6, off);
        ac7 += __shfl_xor(ac7, off);
    }

    // head mean: lane hl pairs with hl^8 (same elem slot, other head)
    float so  = __shfl_xor(s, 8);
    float ot0 = __shfl_xor(ac0, 8);
    float ot1 = __shfl_xor(ac1, 8);
    float ot2 = __shfl_xor(ac2, 8);
    float ot3 = __shfl_xor(ac3, 8);
    float ot4 = __shfl_xor(ac4, 8);
    float ot5 = __shfl_xor(ac5, 8);
    float ot6 = __shfl_xor(ac6, 8);
    float ot7 = __shfl_xor(ac7, 8);

    // node output o = leaky(0.5*(h0+h1) + bias, 0.01) -> LDS (lanes 0-7 of wave)
    if (lane < 8) {
        float inv0 = 1.0f / (s + 1e-16f);    // own = head a
        float inv1 = 1.0f / (so + 1e-16f);   // other = head b
        float4 bv0 = *(const float4*)&bias[lane * 8];
        float4 bv1 = *(const float4*)&bias[lane * 8 + 4];
        float o0 = fmaf(0.5f, fmaf(ac0, inv0, ot0 * inv1), bv0.x);
        float o1 = fmaf(0.5f, fmaf(ac1, inv0, ot1 * inv1), bv0.y);
        float o2 = fmaf(0.5f, fmaf(ac2, inv0, ot2 * inv1), bv0.z);
        float o3 = fmaf(0.5f, fmaf(ac3, inv0, ot3 * inv1), bv0.w);
        float o4 = fmaf(0.5f, fmaf(ac4, inv0, ot4 * inv1), bv1.x);
        float o5 = fmaf(0.5f, fmaf(ac5, inv0, ot5 * inv1), bv1.y);
        float o6 = fmaf(0.5f, fmaf(ac6, inv0, ot6 * inv1), bv1.z);
        float o7 = fmaf(0.5f, fmaf(ac7, inv0, ot7 * inv1), bv1.w);
        o0 = o0 > 0.f ? o0 : 0.01f * o0;
        o1 = o1 > 0.f ? o1 : 0.01f * o1;
        o2 = o2 > 0.f ? o2 : 0.01f * o2;
        o3 = o3 > 0.f ? o3 : 0.01f * o3;
        o4 = o4 > 0.f ? o4 : 0.01f * o4;
        o5 = o5 > 0.f ? o5 : 0.01f * o5;
        o6 = o6 > 0.f ? o6 : 0.01f * o6;
        o7 = o7 > 0.f ? o7 : 0.01f * o7;
        if (FINAL) {
            *(float4*)&sh_o[w][lane * 8]     = make_float4(o0, o1, o2, o3);
            *(float4*)&sh_o[w][lane * 8 + 4] = make_float4(o4, o5, o6, o7);
        } else {
            half8 h;
            h[0] = (_Float16)o0; h[1] = (_Float16)o1;
            h[2] = (_Float16)o2; h[3] = (_Float16)o3;
            h[4] = (_Float16)o4; h[5] = (_Float16)o5;
            h[6] = (_Float16)o6; h[7] = (_Float16)o7;
            *(half8*)&sh_o16[w][lane * 8] = h;
        }
    }

    if (FINAL) {
        // stage Wo (64x64 = 16 KB) into LDS, then per-wave GEMV (verbatim R4)
        __shared__ float wlin[DD * DD];
        {
            int idx = tid * 16;  // 256 threads x 16 floats = 4096
            *(float4*)&wlin[idx]      = *(const float4*)&Wo[idx];
            *(float4*)&wlin[idx + 4]  = *(const float4*)&Wo[idx + 4];
            *(float4*)&wlin[idx + 8]  = *(const float4*)&Wo[idx + 8];
            *(float4*)&wlin[idx + 12] = *(const float4*)&Wo[idx + 12];
        }
        __syncthreads();
        int j = lane;
        float og = bo[j];
#pragma unroll 8
        for (int k = 0; k < DD; ++k) {
            og = fmaf(sh_o[w][k], wlin[k * DD + j], og);
        }
        og = og > 0.f ? og : 0.01f * og;
        out[(size_t)node * DD + j] = og;
    } else {
        // one-barrier fp16 dot2 epilogue: wt LDS [256 cols][PADK], stage once
        __shared__ _Float16 wt[256 * PADK];   // 36 KB
#pragma unroll
        for (int i = 0; i < 8; ++i) {
            int q = tid + 256 * i;            // 0..2047 half8 chunks
            int col = q >> 3;
            int kb = q & 7;
            half8 hv = *(const half8*)&wtn[(size_t)q * 8];  // contiguous global
            *(half8*)&wt[col * PADK + kb * 8] = hv;
        }
        __syncthreads();

        // this lane computes output cols {lane, lane+64, lane+128, lane+192}
        float a0 = bnl[lane];
        float a1 = bnl[lane + 64];
        float a2 = bnr[lane];
        float a3 = bnr[lane + 64];
        const _Float16* o16p = &sh_o16[w][0];
        const _Float16* w0p = &wt[(lane)       * PADK];
        const _Float16* w1p = &wt[(lane + 64)  * PADK];
        const _Float16* w2p = &wt[(lane + 128) * PADK];
        const _Float16* w3p = &wt[(lane + 192) * PADK];

#define KB(kb)                                                             \
        {                                                                  \
            half8 o8 = *(const half8*)&o16p[(kb) * 8];                     \
            half8 wa = *(const half8*)&w0p[(kb) * 8];                      \
            half8 wb = *(const half8*)&w1p[(kb) * 8];                      \
            half8 wc = *(const half8*)&w2p[(kb) * 8];                      \
            half8 wd = *(const half8*)&w3p[(kb) * 8];                      \
            hh2 oA = __builtin_shufflevector(o8, o8, 0, 1);                \
            hh2 oB = __builtin_shufflevector(o8, o8, 2, 3);                \
            hh2 oC = __builtin_shufflevector(o8, o8, 4, 5);                \
            hh2 oD = __builtin_shufflevector(o8, o8, 6, 7);                \
            a0 = FDOT2(__builtin_shufflevector(wa, wa, 0, 1), oA, a0);     \
            a0 = FDOT2(__builtin_shufflevector(wa, wa, 2, 3), oB, a0);     \
            a0 = FDOT2(__builtin_shufflevector(wa, wa, 4, 5), oC, a0);     \
            a0 = FDOT2(__builtin_shufflevector(wa, wa, 6, 7), oD, a0);     \
            a1 = FDOT2(__builtin_shufflevector(wb, wb, 0, 1), oA, a1);     \
            a1 = FDOT2(__builtin_shufflevector(wb, wb, 2, 3), oB, a1);     \
            a1 = FDOT2(__builtin_shufflevector(wb, wb, 4, 5), oC, a1);     \
            a1 = FDOT2(__builtin_shufflevector(wb, wb, 6, 7), oD, a1);     \
            a2 = FDOT2(__builtin_shufflevector(wc, wc, 0, 1), oA, a2);     \
            a2 = FDOT2(__builtin_shufflevector(wc, wc, 2, 3), oB, a2);     \
            a2 = FDOT2(__builtin_shufflevector(wc, wc, 4, 5), oC, a2);     \
            a2 = FDOT2(__builtin_shufflevector(wc, wc, 6, 7), oD, a2);     \
            a3 = FDOT2(__builtin_shufflevector(wd, wd, 0, 1), oA, a3);     \
            a3 = FDOT2(__builtin_shufflevector(wd, wd, 2, 3), oB, a3);     \
            a3 = FDOT2(__builtin_shufflevector(wd, wd, 4, 5), oC, a3);     \
            a3 = FDOT2(__builtin_shufflevector(wd, wd, 6, 7), oD, a3);     \
        }
        KB(0) KB(1) KB(2) KB(3) KB(4) KB(5) KB(6) KB(7)
#undef KB

        size_t nb = (size_t)node * HD;
        xlo[nb + lane]      = (_Float16)a0;
        xlo[nb + lane + 64] = (_Float16)a1;
        xro[nb + lane]      = (_Float16)a2;
        xro[nb + lane + 64] = (_Float16)a3;
    }
}

extern "C" void kernel_launch(void* const* d_in, const int* in_sizes, int n_in,
                              void* d_out, int out_size, void* d_ws, size_t ws_size,
                              hipStream_t stream) {
    const int* edge_index = (const int*)d_in[0];
    const int* src = edge_index;
    const int* dst = edge_index + EE;
    // d_in[1] = edge_weight, unused
    const float* pert = (const float*)d_in[2];
    const float* Wl = (const float*)d_in[3];
    const float* bl = (const float*)d_in[4];
    const float* Wr = (const float*)d_in[5];
    const float* br = (const float*)d_in[6];
    const float* att = (const float*)d_in[7];
    const float* bias = (const float*)d_in[8];
    const float* Wo = (const float*)d_in[9];
    const float* bo = (const float*)d_in[10];
    float* out = (float*)d_out;

    // workspace carve-up (A/B double-buffered fp16 transform tables)
    char* w = (char*)d_ws;
    _Float16* xlA = (_Float16*)w;     w += (size_t)NN * HD * 2;
    _Float16* xrA = (_Float16*)w;     w += (size_t)NN * HD * 2;
    _Float16* xlB = (_Float16*)w;     w += (size_t)NN * HD * 2;
    _Float16* xrB = (_Float16*)w;     w += (size_t)NN * HD * 2;
    int* cnt = (int*)w;               w += (size_t)NN * 4;
    int* csr_src = (int*)w;           w += (size_t)NN * CAP * 4;
    _Float16* wt16 = (_Float16*)w;    w += (size_t)3 * 256 * DD * 2;  // 96 KB

    // memset cnt, then one combined launch: GEMM + scatter + W convert
    hipMemsetAsync(cnt, 0, (size_t)NN * 4, stream);
    prep_kernel<<<GEMM_BLOCKS + SCAT_BLOCKS + WCVT_BLOCKS, 256, 0, stream>>>(
        pert, Wl, bl, Wr, br, xlA, xrA, src, dst, cnt, csr_src, wt16);

    _Float16* xls[2] = {xlA, xlB};
    _Float16* xrs[2] = {xrA, xrB};
    for (int l = 0; l < LL - 1; ++l) {
        fused_aggregate<false><<<NN / NPB, 256, 0, stream>>>(
            xls[l & 1], xrs[l & 1], att + (size_t)l * HD, cnt, csr_src,
            bias + (size_t)l * DD,
            wt16 + (size_t)l * 16384,
            bl + (size_t)(l + 1) * HD, br + (size_t)(l + 1) * HD,
            nullptr, nullptr,
            xls[(l + 1) & 1], xrs[(l + 1) & 1], nullptr);
    }
    fused_aggregate<true><<<NN / NPB, 256, 0, stream>>>(
        xls[(LL - 1) & 1], xrs[(LL - 1) & 1], att + (size_t)(LL - 1) * HD, cnt, csr_src,
        bias + (size_t)(LL - 1) * DD,
        nullptr, nullptr, nullptr,
        Wo, bo, nullptr, nullptr, out);
}